// Round 17
// baseline (217.705 us; speedup 1.0000x reference)
//
#include <hip/hip_runtime.h>
#include <hip/hip_bf16.h>

#define F      128
#define NROWS  2048
#define MROWS  2048
#define MT     32          // m-tiles of 64
#define LOG2E  1.44269504088896340736f

typedef float f32x4 __attribute__((ext_vector_type(4)));

__device__ __forceinline__ void gload16(const float* g, float* l) {
    __builtin_amdgcn_global_load_lds(
        (const __attribute__((address_space(1))) void*)g,
        (__attribute__((address_space(3))) void*)l, 16, 0, 0);
}

// --- Kernel 1: projections + ELU/w2 precompute + w2sum ----------------------
// a = (embeds@W1)[n][g], b = (base@W1)[m][g], w = w2[g]
// PA row-chunk layout: PA[row][ch*16 + 0..7]=p0=(a+1)w, [8..15]=p1=exp(a)w
// BT4 transposed B layout: BT4[(ch*4+q)][m][e], f=q*4+e:
//   f 0..7 = p0=-b*w (g=ch*8+f), f 8..15 = p1=exp(-b) (g=ch*8+f-8)
// w*elu(a-b) + w = med3(p0A + p0B, p1A * p1B, w)
__global__ __launch_bounds__(256) void proj_kernel(
    const float* __restrict__ embeds, const float* __restrict__ base,
    const float* __restrict__ W1, const float* __restrict__ w2,
    float* __restrict__ PA, float* __restrict__ BT4,
    float* __restrict__ w2sum)
{
    const int tid = threadIdx.x;
    const int sub = tid >> 7;
    const int g   = tid & 127;
    const int row = blockIdx.x * 2 + sub;

    __shared__ float xs[2][F];
    {
        const float* src = (row < NROWS) ? &embeds[(size_t)row * F]
                                         : &base[(size_t)(row - NROWS) * F];
        xs[sub][g] = src[g];
    }
    __syncthreads();

    float acc = 0.0f;
#pragma unroll 8
    for (int f = 0; f < F; ++f)
        acc = fmaf(xs[sub][f], W1[f * F + g], acc);

    const float wv = w2[g];
    const int   ch = g >> 3, o = g & 7;
    if (row < NROWS) {
        float* dst = PA + (size_t)row * 256 + ch * 16 + o;
        dst[0] = (acc + 1.0f) * wv;
        dst[8] = __builtin_amdgcn_exp2f(acc * LOG2E) * wv;
    } else {
        const int m  = row - NROWS;
        const int f0 = o, f1 = 8 + o;
        BT4[((size_t)(ch * 4 + (f0 >> 2)) * 2048 + m) * 4 + (f0 & 3)] = -acc * wv;
        BT4[((size_t)(ch * 4 + (f1 >> 2)) * 2048 + m) * 4 + (f1 & 3)] =
            __builtin_amdgcn_exp2f(-acc * LOG2E);
    }

    if (blockIdx.x == 0 && tid < 64) {
        float s = w2[tid] + w2[tid + 64];
#pragma unroll
        for (int k = 1; k < 64; k <<= 1) s += __shfl_xor(s, k);
        if (tid == 0) *w2sum = s;
    }
}

// --- Kernel 2: pair kernel -----------------------------------------------------
// grid (32,32), 256 threads = 4 waves; tile 64(n)x64(m); Rn=Rm=4 (acc 16).
// lane: trl=(l>>4)&3, tc=l&15. Thread rows n = n0 + 4w + trl + 16i; cols
// m = m0 + tc + 16j. A: per-wave PRIVATE LDS strip (16 rows x [8 p0|8 p1|4 pad],
// stride 80B = zero-conflict), staged via global_load_lds, dbuf, per-wave
// vmcnt -> ZERO barriers. B: straight from L2 (BT4, lane-coalesced) into
// ping-pong register quads. DS traffic 2 B/elem-g; B bypasses DS entirely.
__global__ __launch_bounds__(256, 4) void pair_kernel(
    const float* __restrict__ PA, const float* __restrict__ BT4,
    const float* __restrict__ w2, const float* __restrict__ w2sum_p,
    const float* __restrict__ brew, float* __restrict__ partials)
{
    __shared__ float slds[4 * 640];      // 4 waves x 2 bufs x 320 floats = 10.25 KB

    const int tid = threadIdx.x;
    const int w   = tid >> 6, l = tid & 63;
    const int nt  = blockIdx.x, mt = blockIdx.y;
    const int n0  = nt * 64,    m0 = mt * 64;
    const int trl = (l >> 4) & 3;
    const int tc  = l & 15;
    const int wbase = w * 640;

    // A staging sources: slot s -> local row r=s/5 (rows 0..15), 16B-slot rs=s%5
    // (pad slot 4 re-fetches slot 0); global row n = n0 + 4w + (r&3) + 16*(r>>2).
    const float* sA0;
    const float* sA1;
    {
        const int s = l, r = s / 5;
        int rs = s - r * 5; if (rs == 4) rs = 0;
        sA0 = PA + (size_t)(n0 + 4 * w + (r & 3) + 16 * (r >> 2)) * 256 + rs * 4;
    }
    {
        const int s = 64 + l, r = s / 5;
        int rs = s - r * 5; if (rs == 4) rs = 0;
        sA1 = PA + (size_t)(n0 + 4 * w + (r & 3) + 16 * (r >> 2)) * 256 + rs * 4;
    }

#define STAGE_A(CH, BUF) {                                                     \
    float* db = &slds[wbase + (BUF) * 320];                                    \
    gload16(sA0 + (CH) * 16, db);                                              \
    if (l < 16) gload16(sA1 + (CH) * 16, db + 256); }

    // B: per-lane column base; plane offsets are chunk/half constants
    const float* bcol = BT4 + (size_t)(m0 + tc) * 4;
#define LOADB(D1, DE, CH, H) {                                                 \
    _Pragma("unroll")                                                          \
    for (int j = 0; j < 4; ++j) {                                              \
        D1[j] = *(const f32x4*)&bcol[(size_t)((CH) * 4 + (H)) * 8192 + 64 * j];     \
        DE[j] = *(const f32x4*)&bcol[(size_t)((CH) * 4 + 2 + (H)) * 8192 + 64 * j]; \
    } }

    float acc[4][4];
#pragma unroll
    for (int i = 0; i < 4; ++i)
#pragma unroll
        for (int j = 0; j < 4; ++j) acc[i][j] = 0.0f;

#define COMPUTE_H(CH, H, B1, BE, BUF) {                                        \
    const float wq0 = w2[(CH) * 8 + (H) * 4 + 0];                              \
    const float wq1 = w2[(CH) * 8 + (H) * 4 + 1];                              \
    const float wq2 = w2[(CH) * 8 + (H) * 4 + 2];                              \
    const float wq3 = w2[(CH) * 8 + (H) * 4 + 3];                              \
    _Pragma("unroll")                                                          \
    for (int i = 0; i < 4; ++i) {                                              \
        const float* ap = &slds[wbase + (BUF) * 320 + (i * 4 + trl) * 20 + (H) * 4]; \
        const f32x4 a1 = *(const f32x4*)ap;                                    \
        const f32x4 ae = *(const f32x4*)(ap + 8);                              \
        _Pragma("unroll")                                                      \
        for (int j = 0; j < 4; ++j) {                                          \
            const float s0 = __builtin_amdgcn_fmed3f(a1[0] + B1[j][0], ae[0] * BE[j][0], wq0); \
            const float s1 = __builtin_amdgcn_fmed3f(a1[1] + B1[j][1], ae[1] * BE[j][1], wq1); \
            const float s2 = __builtin_amdgcn_fmed3f(a1[2] + B1[j][2], ae[2] * BE[j][2], wq2); \
            const float s3 = __builtin_amdgcn_fmed3f(a1[3] + B1[j][3], ae[3] * BE[j][3], wq3); \
            acc[i][j] += (s0 + s1) + (s2 + s3);                                \
        }                                                                      \
    } }

    f32x4 bX1[4], bXe[4], bY1[4], bYe[4];

    LOADB(bX1, bXe, 0, 0)
    STAGE_A(0, 0)
    asm volatile("s_waitcnt vmcnt(0)" ::: "memory");

#pragma unroll 1
    for (int ch = 0; ch < 16; ++ch) {
        const int buf = ch & 1;
        const int chn = (ch + 1 < 16) ? ch + 1 : 15;
        STAGE_A(chn, buf ^ 1)            // async A stage into other buffer
        LOADB(bY1, bYe, ch, 1)           // prefetch this chunk's h=1 B
        COMPUTE_H(ch, 0, bX1, bXe, buf)
        LOADB(bX1, bXe, chn, 0)          // prefetch next chunk's h=0 B
        COMPUTE_H(ch, 1, bY1, bYe, buf)
        // keep next-chunk B loads from being sunk past the wait (R14 lesson)
        asm volatile("" :: "v"(bX1[0]), "v"(bX1[1]), "v"(bX1[2]), "v"(bX1[3]));
        asm volatile("s_waitcnt vmcnt(0)" ::: "memory");   // per-wave: stage landed
    }
#undef COMPUTE_H
#undef LOADB
#undef STAGE_A

    // --- epilogue: inverse-distance, reduce over tc (low 4 lane bits) ----------
    const float w2sum = *w2sum_p;
    float rsv[4];
#pragma unroll
    for (int j = 0; j < 4; ++j) rsv[j] = brew[m0 + tc + 16 * j];

#pragma unroll
    for (int i = 0; i < 4; ++i) {
        float sw = 0.0f, swr = 0.0f;
#pragma unroll
        for (int j = 0; j < 4; ++j) {
            const float dist = fabsf(acc[i][j] - w2sum);
            const float wgt  = 1.0f / (dist + 1e-4f);
            sw += wgt;
            swr = fmaf(wgt, rsv[j], swr);
        }
#pragma unroll
        for (int k = 1; k < 16; k <<= 1) {
            sw  += __shfl_xor(sw, k);
            swr += __shfl_xor(swr, k);
        }
        if (tc == 0) {
            const int n = n0 + 4 * w + trl + 16 * i;
            partials[((size_t)n * MT + mt) * 2 + 0] = sw;
            partials[((size_t)n * MT + mt) * 2 + 1] = swr;
        }
    }
}

// --- Kernel 3: reduce tile partials, divide ------------------------------------
__global__ __launch_bounds__(256) void finalize_kernel(
    const float* __restrict__ partials, float* __restrict__ out)
{
    const int n = blockIdx.x * 256 + threadIdx.x;
    if (n < NROWS) {
        float sw = 0.0f, swr = 0.0f;
#pragma unroll
        for (int t = 0; t < MT; ++t) {
            sw  += partials[((size_t)n * MT + t) * 2 + 0];
            swr += partials[((size_t)n * MT + t) * 2 + 1];
        }
        out[n] = swr / sw;
    }
}

extern "C" void kernel_launch(void* const* d_in, const int* in_sizes, int n_in,
                              void* d_out, int out_size, void* d_ws, size_t ws_size,
                              hipStream_t stream)
{
    const float* embeds       = (const float*)d_in[0];  // [2048,128]
    const float* base_embeds  = (const float*)d_in[1];  // [2048,128]
    const float* base_rewards = (const float*)d_in[2];  // [2048]
    const float* W1           = (const float*)d_in[3];  // [128,128] (in,out)
    const float* w2           = (const float*)d_in[4];  // [128,1]
    float* out = (float*)d_out;

    // ws: partials [2048*MT*2] | PA [2048*256] | BT4 [64*2048*4] | w2sum[1]
    float* partials = (float*)d_ws;
    float* PA  = partials + (size_t)NROWS * MT * 2;
    float* BT4 = PA + (size_t)NROWS * 256;
    float* w2s = BT4 + (size_t)64 * 2048 * 4;

    proj_kernel<<<(NROWS + MROWS) / 2, 256, 0, stream>>>(
        embeds, base_embeds, W1, w2, PA, BT4, w2s);

    dim3 grid2(NROWS / 64, MROWS / 64);
    pair_kernel<<<grid2, 256, 0, stream>>>(PA, BT4, w2, w2s, base_rewards, partials);

    finalize_kernel<<<(NROWS + 255) / 256, 256, 0, stream>>>(partials, out);
}

// Round 18
// 107.499 us; speedup vs baseline: 2.0252x; 2.0252x over previous
//
#include <hip/hip_runtime.h>
#include <hip/hip_bf16.h>

#define F      128
#define NROWS  2048
#define MROWS  2048
#define MT     32          // m-tiles of 64
#define LOG2E  1.44269504088896340736f

typedef float f32x4 __attribute__((ext_vector_type(4)));

__device__ __forceinline__ void gload16(const float* g, float* l) {
    __builtin_amdgcn_global_load_lds(
        (const __attribute__((address_space(1))) void*)g,
        (__attribute__((address_space(3))) void*)l, 16, 0, 0);
}

// --- Kernel 1: projections + ELU/w2 precompute + w2sum ----------------------
// a = (embeds@W1)[n][g], b = (base@W1)[m][g], w = w2[g]
// Row-chunk layout (both PA and PB): P[row][ch*16 + 0..7]=plane0, [8..15]=plane1
// PA: p0=(a+1)w, p1=exp(a)w ; PB: p0=-b*w, p1=exp(-b)
// w*elu(a-b) + w = med3(p0A + p0B, p1A * p1B, w)
__global__ __launch_bounds__(256) void proj_kernel(
    const float* __restrict__ embeds, const float* __restrict__ base,
    const float* __restrict__ W1, const float* __restrict__ w2,
    float* __restrict__ PA, float* __restrict__ PB,
    float* __restrict__ w2sum)
{
    const int tid = threadIdx.x;
    const int sub = tid >> 7;
    const int g   = tid & 127;
    const int row = blockIdx.x * 2 + sub;

    __shared__ float xs[2][F];
    {
        const float* src = (row < NROWS) ? &embeds[(size_t)row * F]
                                         : &base[(size_t)(row - NROWS) * F];
        xs[sub][g] = src[g];
    }
    __syncthreads();

    float acc = 0.0f;
#pragma unroll 8
    for (int f = 0; f < F; ++f)
        acc = fmaf(xs[sub][f], W1[f * F + g], acc);

    const float wv = w2[g];
    const int   ch = g >> 3, o = g & 7;
    if (row < NROWS) {
        float* dst = PA + (size_t)row * 256 + ch * 16 + o;
        dst[0] = (acc + 1.0f) * wv;
        dst[8] = __builtin_amdgcn_exp2f(acc * LOG2E) * wv;
    } else {
        float* dst = PB + (size_t)(row - NROWS) * 256 + ch * 16 + o;
        dst[0] = -acc * wv;
        dst[8] = __builtin_amdgcn_exp2f(-acc * LOG2E);
    }

    if (blockIdx.x == 0 && tid < 64) {
        float s = w2[tid] + w2[tid + 64];
#pragma unroll
        for (int k = 1; k < 64; k <<= 1) s += __shfl_xor(s, k);
        if (tid == 0) *w2sum = s;
    }
}

// --- Kernel 2: pair kernel -----------------------------------------------------
// grid (16,32), 256 threads = 4 waves; tile 128(n)x64(m); tr=tid>>4, tc=tid&15;
// Rn=8 (rows n0+tr+16i), Rm=4 (cols m0+tc+16j). ZERO barriers.
// B: per-wave private LDS strip [2 buf][64 rows][20 f] (stride 80B = proven
//    zero-conflict), staged by 5 global_load_lds per chunk, read ONCE per chunk
//    into 16 register quads -> DS read traffic 1 B/elem-g.
// A: direct L1 vector loads (4 distinct rows per instr, 16-lane broadcast),
//    aA/aB ping-pong across i (R14-proven pattern).
__global__ __launch_bounds__(256) void pair_kernel(
    const float* __restrict__ PA, const float* __restrict__ PB,
    const float* __restrict__ w2, const float* __restrict__ w2sum_p,
    const float* __restrict__ brew, float* __restrict__ partials)
{
    __shared__ float sB[4][2][1280];   // 40960 B: 4 waves x 2 bufs x (64 rows * 20 f)

    const int tid = threadIdx.x;
    const int w   = tid >> 6, l = tid & 63;
    const int nt  = blockIdx.x, mt = blockIdx.y;
    const int n0  = nt * 128,   m0 = mt * 64;
    const int tr  = tid >> 4,   tc = tid & 15;

    // B staging sources: slot s = k*64+l, row = s/5, 16B-slot rs = s%5 (pad->0)
    const float* bs[5];
#pragma unroll
    for (int k = 0; k < 5; ++k) {
        const int s = k * 64 + l, r = s / 5;
        int rs = s - r * 5; if (rs == 4) rs = 0;
        bs[k] = PB + (size_t)(m0 + r) * 256 + rs * 4;
    }

#define STAGE_B(CH, BUF) {                                                     \
    float* db = &sB[w][BUF][0];                                                \
    gload16(bs[0] + (CH) * 16, db +    0);                                     \
    gload16(bs[1] + (CH) * 16, db +  256);                                     \
    gload16(bs[2] + (CH) * 16, db +  512);                                     \
    gload16(bs[3] + (CH) * 16, db +  768);                                     \
    gload16(bs[4] + (CH) * 16, db + 1024); }

    const float* arow = PA + (size_t)(n0 + tr) * 256;   // lane's base A row

#define LOADA(DST, CH, I) {                                                    \
    const float* ap_ = arow + (size_t)(I) * 16 * 256 + (CH) * 16;              \
    DST[0] = *(const f32x4*)&ap_[0];                                           \
    DST[1] = *(const f32x4*)&ap_[4];                                           \
    DST[2] = *(const f32x4*)&ap_[8];                                           \
    DST[3] = *(const f32x4*)&ap_[12]; }

    float acc[8][4];
#pragma unroll
    for (int i = 0; i < 8; ++i)
#pragma unroll
        for (int j = 0; j < 4; ++j) acc[i][j] = 0.0f;

    f32x4 aA[4], aB[4];

#define COMPUTE(I, A_) {                                                       \
    _Pragma("unroll")                                                          \
    for (int j = 0; j < 4; ++j) {                                              \
        const float s0 = __builtin_amdgcn_fmed3f(A_[0][0] + b1q[j][0][0], A_[2][0] * beq[j][0][0], wlo[0]); \
        const float s1 = __builtin_amdgcn_fmed3f(A_[0][1] + b1q[j][0][1], A_[2][1] * beq[j][0][1], wlo[1]); \
        const float s2 = __builtin_amdgcn_fmed3f(A_[0][2] + b1q[j][0][2], A_[2][2] * beq[j][0][2], wlo[2]); \
        const float s3 = __builtin_amdgcn_fmed3f(A_[0][3] + b1q[j][0][3], A_[2][3] * beq[j][0][3], wlo[3]); \
        const float s4 = __builtin_amdgcn_fmed3f(A_[1][0] + b1q[j][1][0], A_[3][0] * beq[j][1][0], whi[0]); \
        const float s5 = __builtin_amdgcn_fmed3f(A_[1][1] + b1q[j][1][1], A_[3][1] * beq[j][1][1], whi[1]); \
        const float s6 = __builtin_amdgcn_fmed3f(A_[1][2] + b1q[j][1][2], A_[3][2] * beq[j][1][2], whi[2]); \
        const float s7 = __builtin_amdgcn_fmed3f(A_[1][3] + b1q[j][1][3], A_[3][3] * beq[j][1][3], whi[3]); \
        acc[I][j] += ((s0 + s1) + (s2 + s3)) + ((s4 + s5) + (s6 + s7));        \
    } }

// Per chunk: stage next-B (async) -> read B quads from LDS (once) ->
// A ping-pong compute; vmcnt(0) BEFORE the last A-prefetch so it drains only
// the stage + already-needed loads.
#define CHUNK(CH, BUF) {                                                       \
    const int chn_ = ((CH) + 1 < 16) ? (CH) + 1 : 15;                          \
    STAGE_B(chn_, (BUF) ^ 1)                                                   \
    const f32x4 wlo = *(const f32x4*)&w2[(CH) * 8];                            \
    const f32x4 whi = *(const f32x4*)&w2[(CH) * 8 + 4];                        \
    f32x4 b1q[4][2], beq[4][2];                                                \
    _Pragma("unroll")                                                          \
    for (int j = 0; j < 4; ++j) {                                              \
        const float* bp = &sB[w][BUF][(tc + 16 * j) * 20];                     \
        b1q[j][0] = *(const f32x4*)&bp[0];  b1q[j][1] = *(const f32x4*)&bp[4]; \
        beq[j][0] = *(const f32x4*)&bp[8];  beq[j][1] = *(const f32x4*)&bp[12];\
    }                                                                          \
    LOADA(aB, (CH), 1) COMPUTE(0, aA)                                          \
    LOADA(aA, (CH), 2) COMPUTE(1, aB)                                          \
    LOADA(aB, (CH), 3) COMPUTE(2, aA)                                          \
    LOADA(aA, (CH), 4) COMPUTE(3, aB)                                          \
    LOADA(aB, (CH), 5) COMPUTE(4, aA)                                          \
    LOADA(aA, (CH), 6) COMPUTE(5, aB)                                          \
    LOADA(aB, (CH), 7) COMPUTE(6, aA)                                          \
    asm volatile("s_waitcnt vmcnt(0)" ::: "memory");                           \
    LOADA(aA, chn_, 0) COMPUTE(7, aB)                                          \
    }

    STAGE_B(0, 0)
    LOADA(aA, 0, 0)
    asm volatile("s_waitcnt vmcnt(0)" ::: "memory");

#pragma unroll 1
    for (int ch = 0; ch < 16; ch += 2) {
        CHUNK(ch,     0)
        CHUNK(ch + 1, 1)
    }
#undef CHUNK
#undef COMPUTE
#undef LOADA
#undef STAGE_B

    // --- epilogue: inverse-distance, reduce over tc (low 4 lane bits) ----------
    const float w2sum = *w2sum_p;
    float rsv[4];
#pragma unroll
    for (int j = 0; j < 4; ++j) rsv[j] = brew[m0 + tc + 16 * j];

#pragma unroll
    for (int i = 0; i < 8; ++i) {
        float sw = 0.0f, swr = 0.0f;
#pragma unroll
        for (int j = 0; j < 4; ++j) {
            const float dist = fabsf(acc[i][j] - w2sum);
            const float wgt  = 1.0f / (dist + 1e-4f);
            sw += wgt;
            swr = fmaf(wgt, rsv[j], swr);
        }
#pragma unroll
        for (int k = 1; k < 16; k <<= 1) {
            sw  += __shfl_xor(sw, k);
            swr += __shfl_xor(swr, k);
        }
        if (tc == 0) {
            const int n = n0 + tr + 16 * i;
            partials[((size_t)n * MT + mt) * 2 + 0] = sw;
            partials[((size_t)n * MT + mt) * 2 + 1] = swr;
        }
    }
}

// --- Kernel 3: reduce tile partials, divide ------------------------------------
__global__ __launch_bounds__(256) void finalize_kernel(
    const float* __restrict__ partials, float* __restrict__ out)
{
    const int n = blockIdx.x * 256 + threadIdx.x;
    if (n < NROWS) {
        float sw = 0.0f, swr = 0.0f;
#pragma unroll
        for (int t = 0; t < MT; ++t) {
            sw  += partials[((size_t)n * MT + t) * 2 + 0];
            swr += partials[((size_t)n * MT + t) * 2 + 1];
        }
        out[n] = swr / sw;
    }
}

extern "C" void kernel_launch(void* const* d_in, const int* in_sizes, int n_in,
                              void* d_out, int out_size, void* d_ws, size_t ws_size,
                              hipStream_t stream)
{
    const float* embeds       = (const float*)d_in[0];  // [2048,128]
    const float* base_embeds  = (const float*)d_in[1];  // [2048,128]
    const float* base_rewards = (const float*)d_in[2];  // [2048]
    const float* W1           = (const float*)d_in[3];  // [128,128] (in,out)
    const float* w2           = (const float*)d_in[4];  // [128,1]
    float* out = (float*)d_out;

    // ws: partials [2048*MT*2] | PA [2048*256] | PB [2048*256] | w2sum[1]
    float* partials = (float*)d_ws;
    float* PA  = partials + (size_t)NROWS * MT * 2;
    float* PB  = PA + (size_t)NROWS * 256;
    float* w2s = PB + (size_t)MROWS * 256;

    proj_kernel<<<(NROWS + MROWS) / 2, 256, 0, stream>>>(
        embeds, base_embeds, W1, w2, PA, PB, w2s);

    dim3 grid2(NROWS / 128, MROWS / 64);
    pair_kernel<<<grid2, 256, 0, stream>>>(PA, PB, w2, w2s, base_rewards, partials);

    finalize_kernel<<<(NROWS + 255) / 256, 256, 0, stream>>>(partials, out);
}

// Round 19
// 77.106 us; speedup vs baseline: 2.8235x; 1.3942x over previous
//
#include <hip/hip_runtime.h>
#include <hip/hip_bf16.h>

#define F      128
#define NROWS  2048
#define MROWS  2048
#define BN     128         // n-rows per pair block
#define BM     64          // m-cols per pair block
#define MT     (MROWS/BM)  // 32 m-tiles
#define NCH    16          // 16 chunks of 8 g
#define LOG2E  1.44269504088896340736f

// Per-wave private LDS strips (zero-barrier main loop), R12 geometry:
//   row-chunk = 16 data floats (8 p0 | 8 p1) + 4 pad = 20 floats (80 B)
//   stride 80 ≡ 16 (mod 128): measured zero-conflict pattern (R10/R11)
#define ROWF   20
#define BBASE  768
#define BUF_F  2048                      // floats per wave per buffer
#define WAVE_F (2 * BUF_F)               // 4096 floats per wave

typedef float f32x4 __attribute__((ext_vector_type(4)));

__device__ __forceinline__ void gload16(const float* g, float* l) {
    __builtin_amdgcn_global_load_lds(
        (const __attribute__((address_space(1))) void*)g,
        (__attribute__((address_space(3))) void*)l, 16, 0, 0);
}

// --- Kernel 1: projections + ELU/w2 precompute + w2sum ----------------------
// a = (embeds@W1)[n][g], b = (base@W1)[m][g], w = w2[g]
// Global layout: P[row][ch][0..7]=plane0(g=ch*8+o), [8..15]=plane1 (256 f/row)
// PA: p0=(a+1)*w, p1=exp(a)*w ; PB: p0=-b*w, p1=exp(-b)
// w*elu(a-b) + w = med3(p0A + p0B, p1A * p1B, w)
__global__ __launch_bounds__(256) void proj_kernel(
    const float* __restrict__ embeds, const float* __restrict__ base,
    const float* __restrict__ W1, const float* __restrict__ w2,
    float* __restrict__ PA, float* __restrict__ PB,
    float* __restrict__ w2sum)
{
    const int tid = threadIdx.x;
    const int sub = tid >> 7;
    const int g   = tid & 127;
    const int row = blockIdx.x * 2 + sub;

    __shared__ float xs[2][F];
    {
        const float* src = (row < NROWS) ? &embeds[(size_t)row * F]
                                         : &base[(size_t)(row - NROWS) * F];
        xs[sub][g] = src[g];
    }
    __syncthreads();

    float acc = 0.0f;
#pragma unroll 8
    for (int f = 0; f < F; ++f)
        acc = fmaf(xs[sub][f], W1[f * F + g], acc);

    const float wv = w2[g];
    const int   ch = g >> 3, o = g & 7;
    if (row < NROWS) {
        float* dst = PA + (size_t)row * 256 + ch * 16 + o;
        dst[0] = (acc + 1.0f) * wv;
        dst[8] = __builtin_amdgcn_exp2f(acc * LOG2E) * wv;
    } else {
        float* dst = PB + (size_t)(row - NROWS) * 256 + ch * 16 + o;
        dst[0] = -acc * wv;
        dst[8] = __builtin_amdgcn_exp2f(-acc * LOG2E);
    }

    if (blockIdx.x == 0 && tid < 64) {
        float s = w2[tid] + w2[tid + 64];
#pragma unroll
        for (int k = 1; k < 64; k <<= 1) s += __shfl_xor(s, k);
        if (tid == 0) *w2sum = s;
    }
}

// --- Kernel 2: pair kernel -----------------------------------------------------
// R12 structure (barrier-free, per-wave private LDS strips, dbuf, per-wave
// vmcnt) + WAVE PHASE STAGGER: wave w processes chunks in rotated order
// (it + 2w) & 15, so co-resident waves are in different DS/VALU phases and
// the pipes overlap instead of colliding. Sum over g is order-independent.
__global__ __launch_bounds__(256, 2) void pair_kernel(
    const float* __restrict__ PA, const float* __restrict__ PB,
    const float* __restrict__ w2, const float* __restrict__ w2sum_p,
    const float* __restrict__ brew, float* __restrict__ partials)
{
    __shared__ float sbuf[4 * WAVE_F];   // 64 KB
    __shared__ float w2l[F];

    const int tid = threadIdx.x;
    const int w   = tid >> 6, l = tid & 63;
    const int nt  = blockIdx.x, mt = blockIdx.y;
    const int n0  = nt * BN,    m0 = mt * BM;
    const int tc  = tid & 15;
    const int trw = (tid >> 4) & 3;      // thread-row within wave
    const int wbase = w * WAVE_F;

    // staging source precompute: 8 gload instrs per chunk (R12 pattern)
    const float* ssrc[8];
#pragma unroll
    for (int t = 0; t < 8; ++t) {
        int slot, row;
        const float* basep;
        if (t < 3) {
            slot = t * 64 + l;
            const int rl = slot / 5;
            row = n0 + 4 * w + (rl & 3) + 16 * (rl >> 2);
            basep = PA;
        } else {
            slot = (t - 3) * 64 + l;
            row = m0 + slot / 5;
            basep = PB;
        }
        int rs = slot - (slot / 5) * 5;
        if (rs == 4) rs = 0;
        ssrc[t] = basep + (size_t)row * 256 + rs * 4;
    }

#define STAGE(CH, BUF) {                                                   \
    float* db = &sbuf[wbase + (BUF) * BUF_F];                              \
    gload16(ssrc[0] + (CH) * 16, db +    0);                               \
    gload16(ssrc[1] + (CH) * 16, db +  256);                               \
    gload16(ssrc[2] + (CH) * 16, db +  512);                               \
    gload16(ssrc[3] + (CH) * 16, db +  768);                               \
    gload16(ssrc[4] + (CH) * 16, db + 1024);                               \
    gload16(ssrc[5] + (CH) * 16, db + 1280);                               \
    gload16(ssrc[6] + (CH) * 16, db + 1536);                               \
    gload16(ssrc[7] + (CH) * 16, db + 1792); }

    float acc[8][4];
#pragma unroll
    for (int i = 0; i < 8; ++i)
#pragma unroll
        for (int j = 0; j < 4; ++j) acc[i][j] = 0.0f;

    const int ch0 = (2 * w) & 15;        // wave's staggered start chunk
    STAGE(ch0, 0)
    if (tid < F) w2l[tid] = w2[tid];
    __syncthreads();                      // the ONLY barrier (w2l + initial stage)

#pragma unroll 1
    for (int it = 0; it < NCH; ++it) {
        const int ch  = (it + 2 * w) & 15;   // staggered chunk order
        const int buf = it & 1;
        if (it + 1 < NCH) STAGE((ch + 1) & 15, buf ^ 1)

        const float* sa  = &sbuf[wbase + buf * BUF_F];
        const float* sbb = sa + BBASE;

#pragma unroll
        for (int h = 0; h < 2; ++h) {          // two 4-g halves of the 8-g chunk
            const float wq0 = w2l[ch * 8 + h * 4 + 0];
            const float wq1 = w2l[ch * 8 + h * 4 + 1];
            const float wq2 = w2l[ch * 8 + h * 4 + 2];
            const float wq3 = w2l[ch * 8 + h * 4 + 3];
            f32x4 b1v[4], bev[4];
#pragma unroll
            for (int j = 0; j < 4; ++j) {
                const float* bp = sbb + (tc + 16 * j) * ROWF + h * 4;
                b1v[j] = *(const f32x4*)bp;
                bev[j] = *(const f32x4*)(bp + 8);
            }
#pragma unroll
            for (int i = 0; i < 8; ++i) {
                const float* ap = sa + (i * 4 + trw) * ROWF + h * 4;
                const f32x4 a1 = *(const f32x4*)ap;
                const f32x4 ae = *(const f32x4*)(ap + 8);
#pragma unroll
                for (int j = 0; j < 4; ++j) {
                    const float s0 = __builtin_amdgcn_fmed3f(a1.x + b1v[j].x, ae.x * bev[j].x, wq0);
                    const float s1 = __builtin_amdgcn_fmed3f(a1.y + b1v[j].y, ae.y * bev[j].y, wq1);
                    const float s2 = __builtin_amdgcn_fmed3f(a1.z + b1v[j].z, ae.z * bev[j].z, wq2);
                    const float s3 = __builtin_amdgcn_fmed3f(a1.w + b1v[j].w, ae.w * bev[j].w, wq3);
                    acc[i][j] += (s0 + s1) + (s2 + s3);
                }
            }
        }
        // per-wave: ensure our next-buffer stage has landed before reading it
        asm volatile("s_waitcnt vmcnt(0)" ::: "memory");
    }
#undef STAGE

    const float w2sum = *w2sum_p;
    float rsv[4];
#pragma unroll
    for (int j = 0; j < 4; ++j) rsv[j] = brew[m0 + tc + 16 * j];

#pragma unroll
    for (int i = 0; i < 8; ++i) {
        float sw = 0.0f, swr = 0.0f;
#pragma unroll
        for (int j = 0; j < 4; ++j) {
            const float dist = fabsf(acc[i][j] - w2sum);
            const float wgt  = 1.0f / (dist + 1e-4f);
            sw += wgt;
            swr = fmaf(wgt, rsv[j], swr);
        }
#pragma unroll
        for (int k = 1; k < 16; k <<= 1) {   // reduce over tc (low 4 lane bits)
            sw  += __shfl_xor(sw, k);
            swr += __shfl_xor(swr, k);
        }
        if (tc == 0) {
            const int n = n0 + (4 * w + trw) + 16 * i;
            partials[((size_t)n * MT + mt) * 2 + 0] = sw;
            partials[((size_t)n * MT + mt) * 2 + 1] = swr;
        }
    }
}

// --- Kernel 3: reduce tile partials, divide ------------------------------------
__global__ __launch_bounds__(256) void finalize_kernel(
    const float* __restrict__ partials, float* __restrict__ out)
{
    const int n = blockIdx.x * 256 + threadIdx.x;
    if (n < NROWS) {
        float sw = 0.0f, swr = 0.0f;
#pragma unroll
        for (int t = 0; t < MT; ++t) {
            sw  += partials[((size_t)n * MT + t) * 2 + 0];
            swr += partials[((size_t)n * MT + t) * 2 + 1];
        }
        out[n] = swr / sw;
    }
}

extern "C" void kernel_launch(void* const* d_in, const int* in_sizes, int n_in,
                              void* d_out, int out_size, void* d_ws, size_t ws_size,
                              hipStream_t stream)
{
    const float* embeds       = (const float*)d_in[0];  // [2048,128]
    const float* base_embeds  = (const float*)d_in[1];  // [2048,128]
    const float* base_rewards = (const float*)d_in[2];  // [2048]
    const float* W1           = (const float*)d_in[3];  // [128,128] (in,out)
    const float* w2           = (const float*)d_in[4];  // [128,1]
    float* out = (float*)d_out;

    // ws: partials [2048*MT*2] | PA [2048*256] | PB [2048*256] | w2sum[1]
    float* partials = (float*)d_ws;
    float* PA  = partials + (size_t)NROWS * MT * 2;
    float* PB  = PA + (size_t)NROWS * 256;
    float* w2s = PB + (size_t)MROWS * 256;

    proj_kernel<<<(NROWS + MROWS) / 2, 256, 0, stream>>>(
        embeds, base_embeds, W1, w2, PA, PB, w2s);

    dim3 grid2(NROWS / BN, MROWS / BM);
    pair_kernel<<<grid2, 256, 0, stream>>>(PA, PB, w2, w2s, base_rewards, partials);

    finalize_kernel<<<(NROWS + 255) / 256, 256, 0, stream>>>(partials, out);
}